// Round 8
// baseline (403.284 us; speedup 1.0000x reference)
//
#include <hip/hip_runtime.h>
#include <stdint.h>

// Problem constants (B=4, S=2048, K=4096, N=4096 -> M = B*S = 8192)
#define MDIM 8192
#define NDIM 4096
#define KDIM 4096

// GEMM: 256x256 tile, BK=128, 512 threads = 8 waves (2M x 4N), per-wave
// 128x64 via mfma_i32_16x16x64_i8. Double-buffered LDS (128 KiB).
// R5: pipelined reads. R6: 3-bit XOR swizzle (conflicts = 0). R7: balanced
// {8,4,8,4} reads. R8: ONE BARRIER PER TILE (was 4). Measured: ~770 cyc
// pipe-idle per phase with the LDS port at <15% load -> the cost is sync
// lockstep (1 block/CU: at each barrier the whole CU stalls). All 4 stages
// (A+B of t+2) consolidated into P3/P4 so a single LGKM0+WAITV(0)+BAR at
// P2-end certifies every region turnover; waves free-run across phases.
#define BM 256
#define BN 256
#define BK 128
#define NKT (KDIM / BK)   // 32 K-tiles

typedef __attribute__((ext_vector_type(4)))  int i32x4;

#define AS1 __attribute__((address_space(1)))
#define AS3 __attribute__((address_space(3)))

__device__ __forceinline__ int clamp127(int v) {
    return v > 127 ? 127 : (v < -127 ? -127 : v);
}

// ---- x fp32 -> int8, per-row symmetric quant (row = 4096 elems) ----
__global__ __launch_bounds__(256) void quant_x(
        const float* __restrict__ x, const float* __restrict__ sw,
        int8_t* __restrict__ Aq, float* __restrict__ scales) {
    const int row = blockIdx.x;
    const int t   = threadIdx.x;
    const float4* px = (const float4*)(x + (size_t)row * KDIM);

    float4 v[4];
#pragma unroll
    for (int j = 0; j < 4; j++) v[j] = px[t + 256 * j];

    float a = 0.f;
#pragma unroll
    for (int j = 0; j < 4; j++) {
        a = fmaxf(a, fabsf(v[j].x)); a = fmaxf(a, fabsf(v[j].y));
        a = fmaxf(a, fabsf(v[j].z)); a = fmaxf(a, fabsf(v[j].w));
    }
#pragma unroll
    for (int off = 32; off >= 1; off >>= 1)
        a = fmaxf(a, __shfl_xor(a, off));
    __shared__ float red[4];
    if ((t & 63) == 0) red[t >> 6] = a;
    __syncthreads();
    const float amax = fmaxf(fmaxf(red[0], red[1]), fmaxf(red[2], red[3]));
    const float inv  = (amax > 0.f) ? (127.0f / amax) : 0.f;
    if (t == 0) scales[row] = (amax * (1.0f / 127.0f)) * (*sw);

    int* out32 = (int*)(Aq + (size_t)row * KDIM);
#pragma unroll
    for (int j = 0; j < 4; j++) {
        int b0 = clamp127(__float2int_rn(v[j].x * inv));
        int b1 = clamp127(__float2int_rn(v[j].y * inv));
        int b2 = clamp127(__float2int_rn(v[j].z * inv));
        int b3 = clamp127(__float2int_rn(v[j].w * inv));
        out32[t + 256 * j] = (b0 & 255) | ((b1 & 255) << 8) | ((b2 & 255) << 16) | ((b3 & 255) << 24);
    }
}

// ---- qw int32 -> int8 (exact; values already in [-128,127]) ----
__global__ __launch_bounds__(256) void cvt_w(const int* __restrict__ qw, int8_t* __restrict__ Bq) {
    const long i = (long)blockIdx.x * 256 + threadIdx.x;
    int4 a = ((const int4*)qw)[i];
    ((int*)Bq)[i] = (a.x & 255) | ((a.y & 255) << 8) | ((a.z & 255) << 16) | ((a.w & 255) << 24);
}

// ================ 256x256 one-barrier-per-tile i8 GEMM (v8) ================
//
// LDS: [256 rows][128 B]/tile, phys_chunk = logical_chunk ^ (row & 7).
// Linear global_load_lds dest + inverse-swizzled global source (rule #21).
//
// Steady-state per tile t (buf b = t&1; ONE barrier, after P2):
//  P1: rd bF23(t)[4]+aF1a(t)[4] | MMA aF0xbF01
//  P2: rd aF1b(t)[4]            | MMA aF0xbF23 | LGKM0 WAITV(0) BAR
//  P3: rd aF0(t+1)[8]           | MMA aF1xbF01 | stage A(t+2)h0 B(t+2)h0
//  P4: rd bF01(t+1)[4]          | MMA aF1xbF23 | stage A(t+2)h1 B(t+2)h1
// Reg lifetimes (disjoint, single-buffered, = R7): aF0 rd P3(t-1) use P1,P2;
//  aF1 rd P1,P2 use P3,P4; bF01 rd P4(t-1) use P1,P3; bF23 rd P1 use P2,P4.
// vmcnt: at P2(t)-end queue = t+1's 8 loads (issued P3/P4(t-1), >=2 phases
//  old; no younger loads exist) -> WAITV(0) == counted drain, cheap.
// Region/hazard ledger for the SINGLE barrier:
//  - stage A(t+2)->buf(t).A @P3/P4: buf(t).A last read aF1b @P2(t),
//    completed by LGKM0, ordered by BAR(t). SAFE.
//  - stage B(t+2)->buf(t).B @P3/P4: buf(t).B last reads bF23(t)@P1(t) and
//    bF01(t)@P4(t-1); both complete by LGKM0@P2(t) (bF01(t) consumed by
//    MMA@P1(t)); ordered by BAR(t). SAFE.
//  - skew: a fast wave's next stages (t+3 -> buf(t+1)) sit behind BAR(t+1),
//    which every slow wave (still reading buf(t+1) @P3/P4(t) or P1/P2(t+1))
//    must also reach first. SAFE.
//  - visibility: every wave drains its own gload_lds (WAITV(0)) and ds_reads
//    (LGKM0) before BAR -> post-barrier reads see complete tile data.
// Prologue: stage t0+t1 (16 loads), WAITV(8) drains t0, BAR, pre-read
//  aF0(0),bF01(0). Tail (t30,t31): no staging; LGKM0 WAITV(0) BAR @P2(30).

#define BAR()    do { asm volatile("" ::: "memory"); __builtin_amdgcn_s_barrier(); asm volatile("" ::: "memory"); } while (0)
#define LGKM0()  asm volatile("s_waitcnt lgkmcnt(0)" ::: "memory")
#define WAITV(n) asm volatile("s_waitcnt vmcnt(" #n ")" ::: "memory")

#define STAGE_A(buf, h, kt) do { \
    __builtin_amdgcn_global_load_lds((AS1 const void*)(gA + (size_t)((h) * 128) * KDIM + (kt) * 128), \
        (AS3 void*)(sA + (buf) * 32768 + (h) * 16384 + sdst), 16, 0, 0); \
    __builtin_amdgcn_global_load_lds((AS1 const void*)(gA + (size_t)((h) * 128 + 64) * KDIM + (kt) * 128), \
        (AS3 void*)(sA + (buf) * 32768 + (h) * 16384 + 8192 + sdst), 16, 0, 0); \
} while (0)

#define STAGE_B(buf, h, kt) do { \
    __builtin_amdgcn_global_load_lds((AS1 const void*)(gB + (size_t)((h) * 128) * KDIM + (kt) * 128), \
        (AS3 void*)(sB + (buf) * 32768 + (h) * 16384 + sdst), 16, 0, 0); \
    __builtin_amdgcn_global_load_lds((AS1 const void*)(gB + (size_t)((h) * 128 + 64) * KDIM + (kt) * 128), \
        (AS3 void*)(sB + (buf) * 32768 + (h) * 16384 + 8192 + sdst), 16, 0, 0); \
} while (0)

// 16x16x64 fragments: lane l -> row l&15, k-chunk l>>4; rows at 128-B stride.
#define READ_A0(buf) do { \
    _Pragma("unroll") for (int mi = 0; mi < 4; ++mi) \
    _Pragma("unroll") for (int ks = 0; ks < 2; ++ks) \
        aF0[mi][ks] = *(const i32x4*)(sA + (buf) * 32768 + rbA + mi * 2048 + co[ks]); \
} while (0)

#define READ_A1a(buf) do { \
    _Pragma("unroll") for (int mi = 0; mi < 2; ++mi) \
    _Pragma("unroll") for (int ks = 0; ks < 2; ++ks) \
        aF1[mi][ks] = *(const i32x4*)(sA + (buf) * 32768 + rbA + (4 + mi) * 2048 + co[ks]); \
} while (0)

#define READ_A1b(buf) do { \
    _Pragma("unroll") for (int mi = 2; mi < 4; ++mi) \
    _Pragma("unroll") for (int ks = 0; ks < 2; ++ks) \
        aF1[mi][ks] = *(const i32x4*)(sA + (buf) * 32768 + rbA + (4 + mi) * 2048 + co[ks]); \
} while (0)

#define READ_B01(buf) do { \
    _Pragma("unroll") for (int ni = 0; ni < 2; ++ni) \
    _Pragma("unroll") for (int ks = 0; ks < 2; ++ks) \
        bF01[ni][ks] = *(const i32x4*)(sB + (buf) * 32768 + rbB + ni * 2048 + co[ks]); \
} while (0)

#define READ_B23(buf) do { \
    _Pragma("unroll") for (int ni = 0; ni < 2; ++ni) \
    _Pragma("unroll") for (int ks = 0; ks < 2; ++ks) \
        bF23[ni][ks] = *(const i32x4*)(sB + (buf) * 32768 + rbB + (2 + ni) * 2048 + co[ks]); \
} while (0)

// 16 MFMAs per call: 4 mi x 2 nj x 2 ks.  nhofs selects bF01 (0) or bF23 (2).
#define MMA_(AF, accbase, BF, nhofs) do { \
    __builtin_amdgcn_s_setprio(1); \
    _Pragma("unroll") for (int ks = 0; ks < 2; ++ks) \
    _Pragma("unroll") for (int mi = 0; mi < 4; ++mi) \
    _Pragma("unroll") for (int nj = 0; nj < 2; ++nj) \
        acc[(accbase) + mi][(nhofs) + nj] = __builtin_amdgcn_mfma_i32_16x16x64_i8( \
            AF[mi][ks], BF[nj][ks], acc[(accbase) + mi][(nhofs) + nj], 0, 0, 0); \
    __builtin_amdgcn_s_setprio(0); \
} while (0)

__global__ __launch_bounds__(512, 2) void gemm_bt_i8(
        const int8_t* __restrict__ A,    // [M,K] int8
        const int8_t* __restrict__ Bm,   // [N,K] int8
        const float* __restrict__ scales,// [M] = s_m * sw
        const float* __restrict__ bias,  // [N]
        float* __restrict__ C)           // [M,N] fp32
{
    __shared__ __align__(16) int8_t sA[2 * BM * BK];  // 64 KiB
    __shared__ __align__(16) int8_t sB[2 * BN * BK];  // 64 KiB

    const int tid  = threadIdx.x;
    const int wave = tid >> 6;
    const int lane = tid & 63;
    const int wr   = wave >> 2;       // 0..1  (M half)
    const int wc   = wave & 3;        // 0..3  (N quarter)
    const int lr   = lane & 15;       // row within 16-row fragment
    const int lg   = lane >> 4;       // k-group 0..3

    // T1: XCD-aware swizzle over 512 wgs (32 m-tiles x 16 n-tiles); 512%8==0.
    const int orig = blockIdx.y * 16 + blockIdx.x;
    const int nu   = (orig & 7) * 64 + (orig >> 3);
    const int m0   = (nu >> 4) * BM;
    const int n0   = (nu & 15) * BN;

    // ---- staging (linear LDS dest, inverse-swizzled global src) ----
    const int trow = tid >> 3;
    const int slog = (tid & 7) ^ ((tid >> 3) & 7);
    const int8_t* gA = A  + (size_t)(m0 + trow) * KDIM + slog * 16;
    const int8_t* gB = Bm + (size_t)(n0 + trow) * KDIM + slog * 16;
    const int sdst = tid * 16;

    // ---- fragment read addresses ----
    // phys chunk = (ks*4+lg) ^ (lr&7): 16-lane group covers all 8 chunks 2x
    // -> 2-way = free (m136); measured SQ_LDS_BANK_CONFLICT = 0 (R6/R7).
    const int f3 = lr & 7;
    const int rbA = (wr * 128 + lr) * BK;
    const int rbB = (wc * 64  + lr) * BK;
    int co[2];
#pragma unroll
    for (int ks = 0; ks < 2; ++ks) co[ks] = (((ks << 2) | lg) ^ f3) << 4;

    i32x4 acc[8][4];
#pragma unroll
    for (int mi = 0; mi < 8; ++mi)
#pragma unroll
        for (int ni = 0; ni < 4; ++ni)
#pragma unroll
            for (int r = 0; r < 4; ++r) acc[mi][ni][r] = 0;

    i32x4 aF0[4][2];   // rd P3(t-1), used P1,P2(t)
    i32x4 aF1[4][2];   // rd P1,P2(t), used P3,P4(t)
    i32x4 bF01[2][2];  // rd P4(t-1), used P1,P3(t)
    i32x4 bF23[2][2];  // rd P1(t),   used P2,P4(t)

    // ---- prologue: t0 + t1 fully staged; drain t0; pre-read P1(0) operands ----
    STAGE_A(0, 0, 0); STAGE_A(0, 1, 0);
    STAGE_B(0, 0, 0); STAGE_B(0, 1, 0);
    STAGE_A(1, 0, 1); STAGE_A(1, 1, 1);
    STAGE_B(1, 0, 1); STAGE_B(1, 1, 1);
    WAITV(8);          // t0 (8 loads) landed; t1 (8) in flight
    BAR();
    READ_A0(0); READ_B01(0);   // aF0(t0), bF01(t0) for P1; counted lgkm

#pragma unroll 1
    for (int it = 0; it < NKT / 2 - 1; ++it) {     // 15 iters, tiles e=2it, o=e+1 (0..29)
        const int e = 2 * it;
        // ---- tile e (buf0): one barrier, after P2 ----
        READ_B23(0); READ_A1a(0);  MMA_(aF0, 0, bF01, 0);
        READ_A1b(0);               MMA_(aF0, 0, bF23, 2);
        LGKM0(); WAITV(0); BAR();                  // t(e+1) drained & visible
        READ_A0(1);                MMA_(aF1, 4, bF01, 0);  STAGE_A(0, 0, e + 2); STAGE_B(0, 0, e + 2);
        READ_B01(1);               MMA_(aF1, 4, bF23, 2);  STAGE_A(0, 1, e + 2); STAGE_B(0, 1, e + 2);
        // ---- tile o (buf1): one barrier, after P2 ----
        READ_B23(1); READ_A1a(1);  MMA_(aF0, 0, bF01, 0);
        READ_A1b(1);               MMA_(aF0, 0, bF23, 2);
        LGKM0(); WAITV(0); BAR();                  // t(e+2) drained & visible
        READ_A0(0);                MMA_(aF1, 4, bF01, 0);  STAGE_A(1, 0, e + 3); STAGE_B(1, 0, e + 3);
        READ_B01(0);               MMA_(aF1, 4, bF23, 2);  STAGE_A(1, 1, e + 3); STAGE_B(1, 1, e + 3);
    }

    // ---- tail: tile 30 (buf0) + tile 31 (buf1); no staging ----
    READ_B23(0); READ_A1a(0);  MMA_(aF0, 0, bF01, 0);
    READ_A1b(0);               MMA_(aF0, 0, bF23, 2);
    LGKM0(); WAITV(0); BAR();                      // t31 drained & visible
    READ_A0(1);                MMA_(aF1, 4, bF01, 0);
    READ_B01(1);               MMA_(aF1, 4, bF23, 2);
    READ_B23(1); READ_A1a(1);  MMA_(aF0, 0, bF01, 0);
    READ_A1b(1);               MMA_(aF0, 0, bF23, 2);
    MMA_(aF1, 4, bF01, 0);
    MMA_(aF1, 4, bF23, 2);

    // ---- epilogue ----
    // C/D 16x16 layout: col = lr, row = lg*4 + r  [m89/m91, dtype-independent]
#pragma unroll
    for (int mi = 0; mi < 8; ++mi) {
        const int row_base = m0 + wr * 128 + mi * 16 + lg * 4;
        float sc[4];
#pragma unroll
        for (int r = 0; r < 4; ++r) sc[r] = scales[row_base + r];
#pragma unroll
        for (int ni = 0; ni < 4; ++ni) {
            const int col = n0 + wc * 64 + ni * 16 + lr;
            const float bc = bias[col];
#pragma unroll
            for (int r = 0; r < 4; ++r)
                C[(size_t)(row_base + r) * NDIM + col] = (float)acc[mi][ni][r] * sc[r] + bc;
        }
    }
}

// ---- correctness fallback if workspace is too small (not expected to run) ----
__global__ void gemm_naive_f32(const float* __restrict__ x, const int* __restrict__ qw,
                               const float* __restrict__ sw, const float* __restrict__ bias,
                               float* __restrict__ out) {
    size_t id = (size_t)blockIdx.x * blockDim.x + threadIdx.x;
    if (id >= (size_t)MDIM * NDIM) return;
    int m = (int)(id / NDIM);
    int n = (int)(id % NDIM);
    const float* xr = x + (size_t)m * KDIM;
    const int*   wr = qw + (size_t)n * KDIM;
    float acc = 0.f;
    for (int k = 0; k < KDIM; k++) acc += xr[k] * (float)wr[k];
    out[id] = acc * (*sw) + bias[n];
}

extern "C" void kernel_launch(void* const* d_in, const int* in_sizes, int n_in,
                              void* d_out, int out_size, void* d_ws, size_t ws_size,
                              hipStream_t stream) {
    const float* x    = (const float*)d_in[0];
    const int*   qw   = (const int*)d_in[1];
    const float* sw   = (const float*)d_in[2];
    const float* bias = (const float*)d_in[3];
    float* out = (float*)d_out;

    const size_t needA = (size_t)MDIM * KDIM;                  // 32 MiB int8
    const size_t needB = (size_t)NDIM * KDIM;                  // 16 MiB int8
    const size_t needS = (size_t)MDIM * sizeof(float);         // 32 KiB scales

    if (ws_size >= needA + needB + needS) {
        int8_t* Aq = (int8_t*)d_ws;
        int8_t* Bq = Aq + needA;
        float*  scales = (float*)(Bq + needB);

        quant_x<<<MDIM, 256, 0, stream>>>(x, sw, Aq, scales);
        const long nw4 = (long)NDIM * KDIM / 4;
        cvt_w<<<(int)(nw4 / 256), 256, 0, stream>>>(qw, Bq);

        dim3 grid(NDIM / BN, MDIM / BM);                       // (16, 32) = 512 blocks
        gemm_bt_i8<<<grid, 512, 0, stream>>>(Aq, Bq, scales, bias, out);
    } else {
        size_t total = (size_t)MDIM * NDIM;
        gemm_naive_f32<<<(total + 255) / 256, 256, 0, stream>>>(x, qw, sw, bias, out);
    }
}

// Round 9
// 387.960 us; speedup vs baseline: 1.0395x; 1.0395x over previous
//
#include <hip/hip_runtime.h>
#include <stdint.h>

// Problem constants (B=4, S=2048, K=4096, N=4096 -> M = B*S = 8192)
#define MDIM 8192
#define NDIM 4096
#define KDIM 4096

// GEMM: 256x256 tile, BK=128, 512 threads = 8 waves (2M x 4N), per-wave
// 128x64 via mfma_i32_16x16x64_i8. Double-buffered LDS (128 KiB).
// R9: faithful m201 8-phase port. Reads {12,4,8,0} per phase, consumed
// IN-PHASE: reads -> [lgkmcnt(8) if 12] -> BAR -> lgkmcnt(0) -> MFMA -> BAR.
// Overlap comes from the per-wave ramp: after the pre-MFMA barrier each wave
// waits only on ITS OWN reads; early waves' MFMA clusters run while the LDS
// port serves late waves. Explicit LGKM0 keeps each 16-MFMA cluster free of
// compiler-counted internal waits (R1's defect). One half-tile staged per
// phase; provably-safe vmcnt(4) at P4/P8 (each drains exactly one full tile
// before its first read). Swizzle: conflicts measured 0 since R6.
#define BM 256
#define BN 256
#define BK 128
#define NKT (KDIM / BK)   // 32 K-tiles

typedef __attribute__((ext_vector_type(4)))  int i32x4;

#define AS1 __attribute__((address_space(1)))
#define AS3 __attribute__((address_space(3)))

__device__ __forceinline__ int clamp127(int v) {
    return v > 127 ? 127 : (v < -127 ? -127 : v);
}

// ---- x fp32 -> int8, per-row symmetric quant (row = 4096 elems) ----
__global__ __launch_bounds__(256) void quant_x(
        const float* __restrict__ x, const float* __restrict__ sw,
        int8_t* __restrict__ Aq, float* __restrict__ scales) {
    const int row = blockIdx.x;
    const int t   = threadIdx.x;
    const float4* px = (const float4*)(x + (size_t)row * KDIM);

    float4 v[4];
#pragma unroll
    for (int j = 0; j < 4; j++) v[j] = px[t + 256 * j];

    float a = 0.f;
#pragma unroll
    for (int j = 0; j < 4; j++) {
        a = fmaxf(a, fabsf(v[j].x)); a = fmaxf(a, fabsf(v[j].y));
        a = fmaxf(a, fabsf(v[j].z)); a = fmaxf(a, fabsf(v[j].w));
    }
#pragma unroll
    for (int off = 32; off >= 1; off >>= 1)
        a = fmaxf(a, __shfl_xor(a, off));
    __shared__ float red[4];
    if ((t & 63) == 0) red[t >> 6] = a;
    __syncthreads();
    const float amax = fmaxf(fmaxf(red[0], red[1]), fmaxf(red[2], red[3]));
    const float inv  = (amax > 0.f) ? (127.0f / amax) : 0.f;
    if (t == 0) scales[row] = (amax * (1.0f / 127.0f)) * (*sw);

    int* out32 = (int*)(Aq + (size_t)row * KDIM);
#pragma unroll
    for (int j = 0; j < 4; j++) {
        int b0 = clamp127(__float2int_rn(v[j].x * inv));
        int b1 = clamp127(__float2int_rn(v[j].y * inv));
        int b2 = clamp127(__float2int_rn(v[j].z * inv));
        int b3 = clamp127(__float2int_rn(v[j].w * inv));
        out32[t + 256 * j] = (b0 & 255) | ((b1 & 255) << 8) | ((b2 & 255) << 16) | ((b3 & 255) << 24);
    }
}

// ---- qw int32 -> int8 (exact; values already in [-128,127]) ----
__global__ __launch_bounds__(256) void cvt_w(const int* __restrict__ qw, int8_t* __restrict__ Bq) {
    const long i = (long)blockIdx.x * 256 + threadIdx.x;
    int4 a = ((const int4*)qw)[i];
    ((int*)Bq)[i] = (a.x & 255) | ((a.y & 255) << 8) | ((a.z & 255) << 16) | ((a.w & 255) << 24);
}

// ================== 256x256 m201-style 8-phase i8 GEMM (v9) ==================
//
// LDS: [256 rows][128 B]/tile, phys_chunk = logical_chunk ^ (row & 7).
// Linear global_load_lds dest + inverse-swizzled global source (rule #21).
//
// Per tile t (4 phases; e-tiles in buf0, o-tiles in buf1):
//  P1: rd aF0(8)+bF01(4) | stage slot | lgkm(8) BAR lgkm(0) | MMA aF0xbF01 | BAR
//  P2: rd bF23(4)        | stage slot |         BAR lgkm(0) | MMA aF0xbF23 | BAR
//  P3: rd aF1(8)         | stage slot |         BAR lgkm(0) | MMA aF1xbF23 | BAR
//  P4:                   | stage slot, vmcnt(4) BAR         | MMA aF1xbF01 | BAR
// Stage slots per iteration (tiles e,o): P1: o.Ah0, P2: o.Ah1, P3: (e+2).Bh0,
//  P4: (e+2).Bh1, P5: (e+2).Ah0, P6: (e+2).Ah1, P7: (o+2).Bh0, P8: (o+2).Bh1.
// vmcnt queue trace (2 loads/STAGE, steady state; entering P1: [o.B]=4):
//  @P4: [o.B(4), o.A(4), e2.B(4)] = 12 -> WAITV(4) drains tile o fully
//       before P5 reads buf1; leaves [e2.B].
//  @P8: [e2.B(4), e2.A(4), o2.B(4)] = 12 -> WAITV(4) drains tile e+2 fully
//       before next-P1 reads buf0; leaves [o2.B]. Steady state restored.
// Region safety (stage write vs all-wave reads): each stage targets a region
//  whose last ds_read was in phase p' with LGKM0(p') + BAR(p'-end) before the
//  stage issue: o.A (last rd prev-P7) staged P1/P2; e2.B (last rd bF23@P2,
//  bF01@P1) staged P3/P4; e2.A (last rd aF1@P3) staged P5/P6; o2.B (last rd
//  @P6) staged P7/P8. All >=1 closing barrier after the certifying LGKM0.
// Visibility for readers: vmcnt(4)@P4 is followed by TWO barriers before the
//  first dependent read (P5) -> all waves' drains complete. Same @P8 -> P1.
// Prologue: stage t0 full + t1.B; WAITV(4) (drains t0, [t1.B] in flight); BAR.
// Tail: t30 phases stage 31.Ah0/Ah1 @P1/P2, WAITV(0)@P4; t31 pure compute.

#define BAR()    do { asm volatile("" ::: "memory"); __builtin_amdgcn_s_barrier(); asm volatile("" ::: "memory"); } while (0)
#define LGKM0()  asm volatile("s_waitcnt lgkmcnt(0)" ::: "memory")
#define LGKM8()  asm volatile("s_waitcnt lgkmcnt(8)" ::: "memory")
#define WAITV(n) asm volatile("s_waitcnt vmcnt(" #n ")" ::: "memory")

#define STAGE_A(buf, h, kt) do { \
    __builtin_amdgcn_global_load_lds((AS1 const void*)(gA + (size_t)((h) * 128) * KDIM + (kt) * 128), \
        (AS3 void*)(sA + (buf) * 32768 + (h) * 16384 + sdst), 16, 0, 0); \
    __builtin_amdgcn_global_load_lds((AS1 const void*)(gA + (size_t)((h) * 128 + 64) * KDIM + (kt) * 128), \
        (AS3 void*)(sA + (buf) * 32768 + (h) * 16384 + 8192 + sdst), 16, 0, 0); \
} while (0)

#define STAGE_B(buf, h, kt) do { \
    __builtin_amdgcn_global_load_lds((AS1 const void*)(gB + (size_t)((h) * 128) * KDIM + (kt) * 128), \
        (AS3 void*)(sB + (buf) * 32768 + (h) * 16384 + sdst), 16, 0, 0); \
    __builtin_amdgcn_global_load_lds((AS1 const void*)(gB + (size_t)((h) * 128 + 64) * KDIM + (kt) * 128), \
        (AS3 void*)(sB + (buf) * 32768 + (h) * 16384 + 8192 + sdst), 16, 0, 0); \
} while (0)

// 16x16x64 fragments: lane l -> row l&15, k-chunk l>>4; rows at 128-B stride.
#define READ_A0(buf) do { \
    _Pragma("unroll") for (int mi = 0; mi < 4; ++mi) \
    _Pragma("unroll") for (int ks = 0; ks < 2; ++ks) \
        aF0[mi][ks] = *(const i32x4*)(sA + (buf) * 32768 + rbA + mi * 2048 + co[ks]); \
} while (0)

#define READ_A1(buf) do { \
    _Pragma("unroll") for (int mi = 0; mi < 4; ++mi) \
    _Pragma("unroll") for (int ks = 0; ks < 2; ++ks) \
        aF1[mi][ks] = *(const i32x4*)(sA + (buf) * 32768 + rbA + (4 + mi) * 2048 + co[ks]); \
} while (0)

#define READ_B01(buf) do { \
    _Pragma("unroll") for (int ni = 0; ni < 2; ++ni) \
    _Pragma("unroll") for (int ks = 0; ks < 2; ++ks) \
        bF01[ni][ks] = *(const i32x4*)(sB + (buf) * 32768 + rbB + ni * 2048 + co[ks]); \
} while (0)

#define READ_B23(buf) do { \
    _Pragma("unroll") for (int ni = 0; ni < 2; ++ni) \
    _Pragma("unroll") for (int ks = 0; ks < 2; ++ks) \
        bF23[ni][ks] = *(const i32x4*)(sB + (buf) * 32768 + rbB + (2 + ni) * 2048 + co[ks]); \
} while (0)

// 16 MFMAs per cluster: 4 mi x 2 nj x 2 ks.  nhofs selects bF01 (0) / bF23 (2).
#define MMA_(AF, accbase, BF, nhofs) do { \
    __builtin_amdgcn_s_setprio(1); \
    _Pragma("unroll") for (int ks = 0; ks < 2; ++ks) \
    _Pragma("unroll") for (int mi = 0; mi < 4; ++mi) \
    _Pragma("unroll") for (int nj = 0; nj < 2; ++nj) \
        acc[(accbase) + mi][(nhofs) + nj] = __builtin_amdgcn_mfma_i32_16x16x64_i8( \
            AF[mi][ks], BF[nj][ks], acc[(accbase) + mi][(nhofs) + nj], 0, 0, 0); \
    __builtin_amdgcn_s_setprio(0); \
} while (0)

__global__ __launch_bounds__(512, 2) void gemm_bt_i8(
        const int8_t* __restrict__ A,    // [M,K] int8
        const int8_t* __restrict__ Bm,   // [N,K] int8
        const float* __restrict__ scales,// [M] = s_m * sw
        const float* __restrict__ bias,  // [N]
        float* __restrict__ C)           // [M,N] fp32
{
    __shared__ __align__(16) int8_t sA[2 * BM * BK];  // 64 KiB
    __shared__ __align__(16) int8_t sB[2 * BN * BK];  // 64 KiB

    const int tid  = threadIdx.x;
    const int wave = tid >> 6;
    const int lane = tid & 63;
    const int wr   = wave >> 2;       // 0..1  (M half)
    const int wc   = wave & 3;        // 0..3  (N quarter)
    const int lr   = lane & 15;       // row within 16-row fragment
    const int lg   = lane >> 4;       // k-group 0..3

    // T1: XCD-aware swizzle over 512 wgs (32 m-tiles x 16 n-tiles); 512%8==0.
    const int orig = blockIdx.y * 16 + blockIdx.x;
    const int nu   = (orig & 7) * 64 + (orig >> 3);
    const int m0   = (nu >> 4) * BM;
    const int n0   = (nu & 15) * BN;

    // ---- staging (linear LDS dest, inverse-swizzled global src) ----
    const int trow = tid >> 3;
    const int slog = (tid & 7) ^ ((tid >> 3) & 7);
    const int8_t* gA = A  + (size_t)(m0 + trow) * KDIM + slog * 16;
    const int8_t* gB = Bm + (size_t)(n0 + trow) * KDIM + slog * 16;
    const int sdst = tid * 16;

    // ---- fragment read addresses ----
    // phys chunk = (ks*4+lg) ^ (lr&7): 16-lane group covers all 8 chunks 2x
    // -> 2-way = free (m136); measured SQ_LDS_BANK_CONFLICT = 0 (R6-R8).
    const int f3 = lr & 7;
    const int rbA = (wr * 128 + lr) * BK;
    const int rbB = (wc * 64  + lr) * BK;
    int co[2];
#pragma unroll
    for (int ks = 0; ks < 2; ++ks) co[ks] = (((ks << 2) | lg) ^ f3) << 4;

    i32x4 acc[8][4];
#pragma unroll
    for (int mi = 0; mi < 8; ++mi)
#pragma unroll
        for (int ni = 0; ni < 4; ++ni)
#pragma unroll
            for (int r = 0; r < 4; ++r) acc[mi][ni][r] = 0;

    i32x4 aF0[4][2];   // rd P1, used P1,P2
    i32x4 aF1[4][2];   // rd P3, used P3,P4
    i32x4 bF01[2][2];  // rd P1, used P1,P4
    i32x4 bF23[2][2];  // rd P2, used P2,P3

    // ---- prologue: t0 full + t1.B staged; drain t0 ([t1.B]=4 in flight) ----
    STAGE_A(0, 0, 0); STAGE_A(0, 1, 0);
    STAGE_B(0, 0, 0); STAGE_B(0, 1, 0);
    STAGE_B(1, 0, 1); STAGE_B(1, 1, 1);
    WAITV(4);
    BAR();

#pragma unroll 1
    for (int it = 0; it < NKT / 2 - 1; ++it) {     // 15 iters, tiles e=2it, o=e+1 (0..29)
        const int o = 2 * it + 1, e2 = 2 * it + 2, o2 = 2 * it + 3;
        // ---- tile e (buf0) ----
        READ_A0(0); READ_B01(0); STAGE_A(1, 0, o);  LGKM8(); BAR(); LGKM0(); MMA_(aF0, 0, bF01, 0); BAR();
        READ_B23(0);             STAGE_A(1, 1, o);           BAR(); LGKM0(); MMA_(aF0, 0, bF23, 2); BAR();
        READ_A1(0);              STAGE_B(0, 0, e2);          BAR(); LGKM0(); MMA_(aF1, 4, bF23, 2); BAR();
                                 STAGE_B(0, 1, e2); WAITV(4); BAR();         MMA_(aF1, 4, bF01, 0); BAR();
        // ---- tile o (buf1) ----
        READ_A0(1); READ_B01(1); STAGE_A(0, 0, e2); LGKM8(); BAR(); LGKM0(); MMA_(aF0, 0, bF01, 0); BAR();
        READ_B23(1);             STAGE_A(0, 1, e2);          BAR(); LGKM0(); MMA_(aF0, 0, bF23, 2); BAR();
        READ_A1(1);              STAGE_B(1, 0, o2);          BAR(); LGKM0(); MMA_(aF1, 4, bF23, 2); BAR();
                                 STAGE_B(1, 1, o2); WAITV(4); BAR();         MMA_(aF1, 4, bF01, 0); BAR();
    }

    // ---- tail: tile 30 (buf0; stages 31.A, full drain) + tile 31 (buf1) ----
    READ_A0(0); READ_B01(0); STAGE_A(1, 0, 31); LGKM8(); BAR(); LGKM0(); MMA_(aF0, 0, bF01, 0); BAR();
    READ_B23(0);             STAGE_A(1, 1, 31);          BAR(); LGKM0(); MMA_(aF0, 0, bF23, 2); BAR();
    READ_A1(0);                                          BAR(); LGKM0(); MMA_(aF1, 4, bF23, 2); BAR();
                             WAITV(0);                   BAR();          MMA_(aF1, 4, bF01, 0); BAR();
    READ_A0(1); READ_B01(1); LGKM8();                    BAR(); LGKM0(); MMA_(aF0, 0, bF01, 0); BAR();
    READ_B23(1);                                         BAR(); LGKM0(); MMA_(aF0, 0, bF23, 2); BAR();
    READ_A1(1);                                                 LGKM0(); MMA_(aF1, 4, bF23, 2);
    MMA_(aF1, 4, bF01, 0);

    // ---- epilogue ----
    // C/D 16x16 layout: col = lr, row = lg*4 + r  [m89/m91, dtype-independent]
#pragma unroll
    for (int mi = 0; mi < 8; ++mi) {
        const int row_base = m0 + wr * 128 + mi * 16 + lg * 4;
        float sc[4];
#pragma unroll
        for (int r = 0; r < 4; ++r) sc[r] = scales[row_base + r];
#pragma unroll
        for (int ni = 0; ni < 4; ++ni) {
            const int col = n0 + wc * 64 + ni * 16 + lr;
            const float bc = bias[col];
#pragma unroll
            for (int r = 0; r < 4; ++r)
                C[(size_t)(row_base + r) * NDIM + col] = (float)acc[mi][ni][r] * sc[r] + bc;
        }
    }
}

// ---- correctness fallback if workspace is too small (not expected to run) ----
__global__ void gemm_naive_f32(const float* __restrict__ x, const int* __restrict__ qw,
                               const float* __restrict__ sw, const float* __restrict__ bias,
                               float* __restrict__ out) {
    size_t id = (size_t)blockIdx.x * blockDim.x + threadIdx.x;
    if (id >= (size_t)MDIM * NDIM) return;
    int m = (int)(id / NDIM);
    int n = (int)(id % NDIM);
    const float* xr = x + (size_t)m * KDIM;
    const int*   wr = qw + (size_t)n * KDIM;
    float acc = 0.f;
    for (int k = 0; k < KDIM; k++) acc += xr[k] * (float)wr[k];
    out[id] = acc * (*sw) + bias[n];
}

extern "C" void kernel_launch(void* const* d_in, const int* in_sizes, int n_in,
                              void* d_out, int out_size, void* d_ws, size_t ws_size,
                              hipStream_t stream) {
    const float* x    = (const float*)d_in[0];
    const int*   qw   = (const int*)d_in[1];
    const float* sw   = (const float*)d_in[2];
    const float* bias = (const float*)d_in[3];
    float* out = (float*)d_out;

    const size_t needA = (size_t)MDIM * KDIM;                  // 32 MiB int8
    const size_t needB = (size_t)NDIM * KDIM;                  // 16 MiB int8
    const size_t needS = (size_t)MDIM * sizeof(float);         // 32 KiB scales

    if (ws_size >= needA + needB + needS) {
        int8_t* Aq = (int8_t*)d_ws;
        int8_t* Bq = Aq + needA;
        float*  scales = (float*)(Bq + needB);

        quant_x<<<MDIM, 256, 0, stream>>>(x, sw, Aq, scales);
        const long nw4 = (long)NDIM * KDIM / 4;
        cvt_w<<<(int)(nw4 / 256), 256, 0, stream>>>(qw, Bq);

        dim3 grid(NDIM / BN, MDIM / BM);                       // (16, 32) = 512 blocks
        gemm_bt_i8<<<grid, 512, 0, stream>>>(Aq, Bq, scales, bias, out);
    } else {
        size_t total = (size_t)MDIM * NDIM;
        gemm_naive_f32<<<(total + 255) / 256, 256, 0, stream>>>(x, qw, sw, bias, out);
    }
}